// Round 3
// baseline (6486.272 us; speedup 1.0000x reference)
//
#include <hip/hip_runtime.h>
#include <hip/hip_bf16.h>

#define VOCAB 50257
#define EMBD  256
#define HID   512
#define BATCH 64
#define SEQ   512

typedef short bf16x8 __attribute__((ext_vector_type(8)));
typedef float f32x4  __attribute__((ext_vector_type(4)));

__device__ inline short f2b(float f) {            // RNE float->bf16
    union { float f; unsigned u; } v; v.f = f;
    unsigned r = v.u + 0x7FFFu + ((v.u >> 16) & 1u);
    return (short)(r >> 16);
}
__device__ inline unsigned pack2_trunc(float lo, float hi) {  // 2 floats -> packed bf16x2 (truncate)
    union { float f; unsigned u; } a, b; a.f = lo; b.f = hi;
    return __builtin_amdgcn_perm(b.u, a.u, 0x07060302);
}
__device__ inline float fast_tanh(float x) {
    x = fminf(fmaxf(x, -15.f), 15.f);
    float e = __expf(2.f * x);
    return (e - 1.f) / (e + 1.f);
}
__device__ inline float fast_sig(float x) { return 1.f / (1.f + __expf(-x)); }

__device__ inline void load_x_frags(const float* __restrict__ emb, int idxv, int quad, bf16x8* Ax) {
#pragma unroll
    for (int kt = 0; kt < 8; ++kt) {
        const float* p = emb + (size_t)idxv * EMBD + kt * 32 + quad * 8;
        float4 e0 = *(const float4*)(p);
        float4 e1 = *(const float4*)(p + 4);
        union { bf16x8 v; unsigned u[4]; } f;
        f.u[0] = pack2_trunc(e0.x, e0.y);
        f.u[1] = pack2_trunc(e0.z, e0.w);
        f.u[2] = pack2_trunc(e1.x, e1.y);
        f.u[3] = pack2_trunc(e1.z, e1.w);
        Ax[kt] = f.v;
    }
}

// ---------------------------------------------------------------------------
// Persistent LSTM, dual-chain: 64 WGs = 2 pair-sets x 32 WGs (16 h-cols each).
// Each WG serves TWO independent 16-row batch chains (A=pair*2, B=pair*2+1),
// interleaved so one chain's h-store propagation hides under the other's
// compute phase. h exchange: self-validating 8B units {2 x bf16, step tag}
// stored with ONE relaxed agent atomic — no release/ack, no separate flag;
// the consumer's poll IS the data load. Parity double-buffer (t&1).
// ---------------------------------------------------------------------------
__global__ __launch_bounds__(256, 1) void lstm_kernel(
    const int* __restrict__ idx, const float* __restrict__ emb,
    const float* __restrict__ Wi, const float* __restrict__ Wh,
    const float* __restrict__ bvec,
    unsigned long long* __restrict__ hbuf /* [2][4][32][16][8] tagged units */,
    unsigned short* __restrict__ hfinal /* [64][512] bf16 */)
{
    const int wgid = blockIdx.x;       // 64 WGs
    const int pair = wgid >> 5;        // 0: groups 0,1   1: groups 2,3
    const int j    = wgid & 31;
    const int tid  = threadIdx.x;
    const int lane = tid & 63;
    const int gate = tid >> 6;         // wave id = gate (i,f,g,o)
    const int quad = lane >> 4;
    const int l16  = lane & 15;
    const int col  = gate * HID + j * 16 + l16;

    __shared__ float gbuf[4][16][16];
    __shared__ __align__(16) unsigned short hstage[16][HID + 8];  // stride 1040B: frag reads 2-way (free)

    // persistent B fragments (shared by both chains): Wh k=512, Wi k=256
    bf16x8 Bh[16], Bx[8];
#pragma unroll
    for (int kt = 0; kt < 16; ++kt)
#pragma unroll
        for (int i = 0; i < 8; ++i)
            Bh[kt][i] = f2b(Wh[(size_t)(kt * 32 + quad * 8 + i) * 2048 + col]);
#pragma unroll
    for (int kt = 0; kt < 8; ++kt)
#pragma unroll
        for (int i = 0; i < 8; ++i)
            Bx[kt][i] = f2b(Wi[(size_t)(kt * 32 + quad * 8 + i) * 2048 + col]);
    const float bv = bvec[col];

    const int g0 = pair * 2, g1 = pair * 2 + 1;
    const int r0 = g0 * 16 + l16, r1 = g1 * 16 + l16;   // batch rows for A frags
    bf16x8 Ax0[8], Ax1[8];
    load_x_frags(emb, idx[r0 * SEQ], quad, Ax0);
    load_x_frags(emb, idx[r1 * SEQ], quad, Ax1);

    // update-thread (tid<128) register c-state: [chain][2 cells]
    const int rr = tid >> 3, uu = tid & 7, c2 = uu * 2;
    float cs[2][2] = {{0.f, 0.f}, {0.f, 0.f}};

    for (int t = 0; t < SEQ; ++t) {
#pragma unroll
        for (int c = 0; c < 2; ++c) {
            const int grp = pair * 2 + c;
            unsigned long long* const rbase =
                hbuf + ((size_t)((t & 1) * 4 + grp)) * 4096;   // 32 j * 128 units

            unsigned long long v[16];
            if (t > 0) {       // issue staging loads early (overlap with x-MFMA)
#pragma unroll
                for (int i = 0; i < 16; ++i)
                    v[i] = __hip_atomic_load(rbase + i * 256 + tid,
                                             __ATOMIC_RELAXED, __HIP_MEMORY_SCOPE_AGENT);
            }

            // ---- x contribution (Ax prefetched in previous phase) ----
            f32x4 a0 = {0.f, 0.f, 0.f, 0.f}, a1 = {0.f, 0.f, 0.f, 0.f};
#pragma unroll
            for (int kt = 0; kt < 8; kt += 2) {
                a0 = __builtin_amdgcn_mfma_f32_16x16x32_bf16(c ? Ax1[kt] : Ax0[kt], Bx[kt], a0, 0, 0, 0);
                a1 = __builtin_amdgcn_mfma_f32_16x16x32_bf16(c ? Ax1[kt + 1] : Ax0[kt + 1], Bx[kt + 1], a1, 0, 0, 0);
            }

            if (t > 0) {
                // ---- tag-validated staging: poll IS the data load ----
                const unsigned tg = (unsigned)t;
                unsigned pend = 0xFFFFu;
                while (true) {
#pragma unroll
                    for (int i = 0; i < 16; ++i) {
                        if ((pend & (1u << i)) && (unsigned)(v[i] >> 32) == tg) {
                            pend &= ~(1u << i);
                            const int L = i * 256 + tid;
                            *(unsigned*)&hstage[(L >> 3) & 15][(L >> 7) * 16 + (L & 7) * 2] =
                                (unsigned)v[i];
                        }
                    }
                    if (__builtin_expect(pend == 0, 1)) break;
#pragma unroll
                    for (int i = 0; i < 16; ++i)
                        if (pend & (1u << i))
                            v[i] = __hip_atomic_load(rbase + i * 256 + tid,
                                                     __ATOMIC_RELAXED, __HIP_MEMORY_SCOPE_AGENT);
                }
            }
            __syncthreads();   // barrier1: hstage ready (also orders gbuf reuse at t==0)

            if (t > 0) {
#pragma unroll
                for (int kt = 0; kt < 16; kt += 2) {
                    bf16x8 ha = *(const bf16x8*)&hstage[l16][kt * 32 + quad * 8];
                    bf16x8 hb = *(const bf16x8*)&hstage[l16][(kt + 1) * 32 + quad * 8];
                    a0 = __builtin_amdgcn_mfma_f32_16x16x32_bf16(ha, Bh[kt], a0, 0, 0, 0);
                    a1 = __builtin_amdgcn_mfma_f32_16x16x32_bf16(hb, Bh[kt + 1], a1, 0, 0, 0);
                }
            }

            // ---- activation: C layout row=(quad*4+r), col=l16 ----
#pragma unroll
            for (int r = 0; r < 4; ++r) {
                float z = a0[r] + a1[r] + bv;
                gbuf[gate][quad * 4 + r][l16] = (gate == 2) ? fast_tanh(z) : fast_sig(z);
            }
            __syncthreads();   // barrier2: gates ready

            // ---- c/h update (waves 0,1); tagged 8B store, no release needed ----
            if (tid < 128) {
                float h0, h1;
                {
                    float i0 = gbuf[0][rr][c2], f0 = gbuf[1][rr][c2];
                    float gg = gbuf[2][rr][c2], o0 = gbuf[3][rr][c2];
                    float cc = f0 * cs[c][0] + i0 * gg;
                    cs[c][0] = cc;
                    h0 = o0 * fast_tanh(cc);
                }
                {
                    float i1 = gbuf[0][rr][c2 + 1], f1 = gbuf[1][rr][c2 + 1];
                    float gg = gbuf[2][rr][c2 + 1], o1 = gbuf[3][rr][c2 + 1];
                    float cc = f1 * cs[c][1] + i1 * gg;
                    cs[c][1] = cc;
                    h1 = o1 * fast_tanh(cc);
                }
                unsigned pv = (unsigned)(unsigned short)f2b(h0) |
                              ((unsigned)(unsigned short)f2b(h1) << 16);
                unsigned long long val = (unsigned long long)pv |
                                         ((unsigned long long)(unsigned)(t + 1) << 32);
                unsigned long long* dst = hbuf +
                    ((size_t)(((t + 1) & 1) * 4 + grp) * 32 + j) * 128 + rr * 8 + uu;
                __hip_atomic_store(dst, val, __ATOMIC_RELAXED, __HIP_MEMORY_SCOPE_AGENT);
                if (t == SEQ - 1)
                    *(unsigned*)&hfinal[(size_t)(grp * 16 + rr) * HID + j * 16 + c2] = pv;
            }

            // ---- prefetch next x for this chain (drains during other phase) ----
            if (t + 1 < SEQ) {
                int nx = idx[(c ? r1 : r0) * SEQ + t + 1];
                load_x_frags(emb, nx, quad, c ? Ax1 : Ax0);
            }
        }
    }
}

// ---------------------------------------------------------------------------
// y = tanh(A[64x512](bf16) @ W[512x512](f32) + bias) -> out bf16 [64][512]
// ---------------------------------------------------------------------------
__global__ __launch_bounds__(256, 1) void gemm_tanh_kernel(
    const unsigned short* __restrict__ A, const float* __restrict__ W,
    const float* __restrict__ bias, unsigned short* __restrict__ out)
{
    const int tid = threadIdx.x, lane = tid & 63, wave = tid >> 6;
    const int quad = lane >> 4, l16 = lane & 15;
    const int col = blockIdx.x * 16 + l16;
    bf16x8 Bw[16];
#pragma unroll
    for (int kt = 0; kt < 16; ++kt)
#pragma unroll
        for (int i = 0; i < 8; ++i)
            Bw[kt][i] = f2b(W[(size_t)(kt * 32 + quad * 8 + i) * HID + col]);
    f32x4 acc = {0.f, 0.f, 0.f, 0.f};
#pragma unroll
    for (int kt = 0; kt < 16; ++kt) {
        bf16x8 a = *(const bf16x8*)(A + (size_t)(wave * 16 + l16) * HID + kt * 32 + quad * 8);
        acc = __builtin_amdgcn_mfma_f32_16x16x32_bf16(a, Bw[kt], acc, 0, 0, 0);
    }
    const float bvv = bias[col];
#pragma unroll
    for (int r = 0; r < 4; ++r) {
        float y = fast_tanh(acc[r] + bvv);
        out[(size_t)(wave * 16 + quad * 4 + r) * HID + col] = (unsigned short)f2b(y);
    }
}

// ---------------------------------------------------------------------------
// logits = A[64x512](bf16) @ W3[512x50257](f32) + b3 -> f32 [64][50257]
// LDS-staged W3 tiles: coalesced float4 HBM reads.
// ---------------------------------------------------------------------------
__global__ __launch_bounds__(256, 2) void logits_kernel(
    const unsigned short* __restrict__ A, const float* __restrict__ W3,
    const float* __restrict__ b3, float* __restrict__ outL)
{
    const int tid = threadIdx.x, lane = tid & 63, wave = tid >> 6;
    const int quad = lane >> 4, l16 = lane & 15;
    const int c0 = blockIdx.x * 64;
    const int col = c0 + wave * 16 + l16;
    const bool cok = col < VOCAB;
    const int colc = cok ? col : (VOCAB - 1);

    __shared__ unsigned short wt[256][68];

    f32x4 acc[4];
#pragma unroll
    for (int rt = 0; rt < 4; ++rt) acc[rt] = (f32x4){0.f, 0.f, 0.f, 0.f};

    const int kr = tid >> 4;
    const int cg = (tid & 15) * 4;

    for (int kc = 0; kc < 2; ++kc) {
#pragma unroll 4
        for (int it = 0; it < 16; ++it) {
            const int k = it * 16 + kr;
            const int gc = c0 + cg;
            float4 wv;
            if (gc + 3 < VOCAB) {
                wv = *(const float4*)&W3[(size_t)(kc * 256 + k) * VOCAB + gc];
            } else {
                const float* Wr = &W3[(size_t)(kc * 256 + k) * VOCAB];
                wv.x = (gc + 0 < VOCAB) ? Wr[gc + 0] : 0.f;
                wv.y = (gc + 1 < VOCAB) ? Wr[gc + 1] : 0.f;
                wv.z = (gc + 2 < VOCAB) ? Wr[gc + 2] : 0.f;
                wv.w = (gc + 3 < VOCAB) ? Wr[gc + 3] : 0.f;
            }
            unsigned short* d = &wt[k][cg];
            d[0] = (unsigned short)f2b(wv.x);
            d[1] = (unsigned short)f2b(wv.y);
            d[2] = (unsigned short)f2b(wv.z);
            d[3] = (unsigned short)f2b(wv.w);
        }
        __syncthreads();
        bf16x8 Bw[8];
#pragma unroll
        for (int kt = 0; kt < 8; ++kt)
#pragma unroll
            for (int i = 0; i < 8; ++i)
                Bw[kt][i] = (short)wt[kt * 32 + quad * 8 + i][wave * 16 + l16];
#pragma unroll
        for (int rt = 0; rt < 4; ++rt)
#pragma unroll
            for (int kt = 0; kt < 8; ++kt) {
                bf16x8 a = *(const bf16x8*)(A + (size_t)(rt * 16 + l16) * HID +
                                            kc * 256 + kt * 32 + quad * 8);
                acc[rt] = __builtin_amdgcn_mfma_f32_16x16x32_bf16(a, Bw[kt], acc[rt], 0, 0, 0);
            }
        __syncthreads();
    }
    const float bvv = b3[colc];
    if (cok) {
#pragma unroll
        for (int rt = 0; rt < 4; ++rt)
#pragma unroll
            for (int r = 0; r < 4; ++r)
                outL[(size_t)(rt * 16 + quad * 4 + r) * VOCAB + col] = acc[rt][r] + bvv;
    }
}

// ---------------------------------------------------------------------------
// row-wise log_softmax over [64][50257], float4 main loop
// ---------------------------------------------------------------------------
__global__ __launch_bounds__(256, 1) void lsm_kernel(
    const float* __restrict__ lg, float* __restrict__ out)
{
    const int row = blockIdx.x;
    const float* L = lg + (size_t)row * VOCAB;
    const float4* L4 = (const float4*)L;
    const int nv4 = VOCAB / 4;

    float m = -1e30f;
    for (int i = threadIdx.x; i < nv4; i += 256) {
        float4 v = L4[i];
        m = fmaxf(fmaxf(fmaxf(m, v.x), fmaxf(v.y, v.z)), v.w);
    }
    if (threadIdx.x == 0) m = fmaxf(m, L[VOCAB - 1]);
#pragma unroll
    for (int o = 32; o; o >>= 1) m = fmaxf(m, __shfl_xor(m, o));
    __shared__ float red[4], red2[4];
    if ((threadIdx.x & 63) == 0) red[threadIdx.x >> 6] = m;
    __syncthreads();
    m = fmaxf(fmaxf(red[0], red[1]), fmaxf(red[2], red[3]));

    float s = 0.f;
    for (int i = threadIdx.x; i < nv4; i += 256) {
        float4 v = L4[i];
        s += __expf(v.x - m) + __expf(v.y - m) + __expf(v.z - m) + __expf(v.w - m);
    }
    if (threadIdx.x == 0) s += __expf(L[VOCAB - 1] - m);
#pragma unroll
    for (int o = 32; o; o >>= 1) s += __shfl_xor(s, o);
    if ((threadIdx.x & 63) == 0) red2[threadIdx.x >> 6] = s;
    __syncthreads();
    s = red2[0] + red2[1] + red2[2] + red2[3];
    const float ls = m + __logf(s);

    float* O = out + (size_t)row * VOCAB;
    float4* O4 = (float4*)O;
    for (int i = threadIdx.x; i < nv4; i += 256) {
        float4 v = L4[i];
        O4[i] = (float4){v.x - ls, v.y - ls, v.z - ls, v.w - ls};
    }
    if (threadIdx.x == 0) O[VOCAB - 1] = L[VOCAB - 1] - ls;
}

extern "C" void kernel_launch(void* const* d_in, const int* in_sizes, int n_in,
                              void* d_out, int out_size, void* d_ws, size_t ws_size,
                              hipStream_t stream) {
    (void)in_sizes; (void)n_in; (void)out_size; (void)ws_size;
    const int*   idx = (const int*)d_in[0];
    const float* emb = (const float*)d_in[1];
    const float* Wi  = (const float*)d_in[2];
    const float* Wh  = (const float*)d_in[3];
    const float* b   = (const float*)d_in[4];
    const float* W1  = (const float*)d_in[5];
    const float* b1  = (const float*)d_in[6];
    const float* W2  = (const float*)d_in[7];
    const float* b2  = (const float*)d_in[8];
    const float* W3  = (const float*)d_in[9];
    const float* b3  = (const float*)d_in[10];
    float* out = (float*)d_out;

    // ws layout (time-disjoint aliasing, total 13,127,936 B <= proven R2 footprint):
    //   [0, 256K)        hbuf   (lstm only)  -- reused after lstm by y1/y2
    //   [0, 64K)         y1     (gemm1 out / gemm2 in)
    //   [64K, 128K)      y2     (gemm2 out / logits in)
    //   [256K, 320K)     hfinal (lstm out / gemm1 in) -- aliases logits head (dead by then)
    //   [256K, 256K+12.87M) logits (logits out / lsm in)
    char* w = (char*)d_ws;
    unsigned long long* hbuf   = (unsigned long long*)w;
    unsigned short*     y1     = (unsigned short*)w;
    unsigned short*     y2     = (unsigned short*)(w + 65536);
    unsigned short*     hfinal = (unsigned short*)(w + 262144);
    float*              logits = (float*)(w + 262144);

    lstm_kernel<<<64, 256, 0, stream>>>(idx, emb, Wi, Wh, b, hbuf, hfinal);
    gemm_tanh_kernel<<<HID / 16, 256, 0, stream>>>(hfinal, W1, b1, y1);
    gemm_tanh_kernel<<<HID / 16, 256, 0, stream>>>(y1, W2, b2, y2);
    logits_kernel<<<(VOCAB + 63) / 64, 256, 0, stream>>>(y2, W3, b3, logits);
    lsm_kernel<<<BATCH, 256, 0, stream>>>(logits, out);
}

// Round 4
// 2182.878 us; speedup vs baseline: 2.9714x; 2.9714x over previous
//
#include <hip/hip_runtime.h>
#include <hip/hip_bf16.h>

#define VOCAB 50257
#define EMBD  256
#define HID   512
#define BATCH 64
#define SEQ   512

typedef short bf16x8 __attribute__((ext_vector_type(8)));
typedef float f32x4  __attribute__((ext_vector_type(4)));

__device__ inline short f2b(float f) {            // RNE float->bf16
    union { float f; unsigned u; } v; v.f = f;
    unsigned r = v.u + 0x7FFFu + ((v.u >> 16) & 1u);
    return (short)(r >> 16);
}
__device__ inline unsigned pack2_trunc(float lo, float hi) {  // 2 floats -> packed bf16x2 (truncate)
    union { float f; unsigned u; } a, b; a.f = lo; b.f = hi;
    return __builtin_amdgcn_perm(b.u, a.u, 0x07060302);
}
__device__ inline float fast_tanh(float x) {
    x = fminf(fmaxf(x, -15.f), 15.f);
    float e = __expf(2.f * x);
    return (e - 1.f) / (e + 1.f);
}
__device__ inline float fast_sig(float x) { return 1.f / (1.f + __expf(-x)); }

__device__ inline void load_x_frags(const float* __restrict__ emb, int idxv, int quad, bf16x8* Ax) {
#pragma unroll
    for (int kt = 0; kt < 8; ++kt) {
        const float* p = emb + (size_t)idxv * EMBD + kt * 32 + quad * 8;
        float4 e0 = *(const float4*)(p);
        float4 e1 = *(const float4*)(p + 4);
        union { bf16x8 v; unsigned u[4]; } f;
        f.u[0] = pack2_trunc(e0.x, e0.y);
        f.u[1] = pack2_trunc(e0.z, e0.w);
        f.u[2] = pack2_trunc(e1.x, e1.y);
        f.u[3] = pack2_trunc(e1.z, e1.w);
        Ax[kt] = f.v;
    }
}

// ---------------------------------------------------------------------------
// Persistent LSTM: 128 WGs = 4 groups (16 batch rows) x 32 WGs (16 h-cols).
// Wave g computes gate g for its 16 cols (register-resident Wh/Wi frags).
// h exchange: self-validating 8B units {step tag, 2 x bf16} stored with ONE
// relaxed agent atomic (no release/ack, no flags, no barrier after stores).
// Consumer staging: wave w owns rows 4w..4w+3; 16 units/lane; wave-uniform
// batched retry via ballot. Parity double-buffer; tags disambiguate steps, so
// no workspace init is needed (0xAA poison never matches a tag).
// ---------------------------------------------------------------------------
__global__ __launch_bounds__(256, 1) void lstm_kernel(
    const int* __restrict__ idx, const float* __restrict__ emb,
    const float* __restrict__ Wi, const float* __restrict__ Wh,
    const float* __restrict__ bvec,
    unsigned long long* __restrict__ hbuf /* [2][4][16][256] tagged units */,
    unsigned short* __restrict__ hfinal /* [64][512] bf16 */)
{
    const int wgid = blockIdx.x;       // 128 WGs
    const int grp  = wgid >> 5;        // batch group 0..3
    const int j    = wgid & 31;        // 16-col slice
    const int tid  = threadIdx.x;
    const int lane = tid & 63;
    const int gate = tid >> 6;         // wave id = gate (i,f,g,o)
    const int quad = lane >> 4;
    const int l16  = lane & 15;
    const int col  = gate * HID + j * 16 + l16;
    const int arow = grp * 16 + l16;   // batch row for A fragments

    __shared__ float gbuf[4][16][16];
    __shared__ __align__(16) unsigned short hstage[16][HID + 8];  // stride 1040B

    // persistent B fragments: Wh k=512, Wi k=256 (RNE converted once)
    bf16x8 Bh[16], Bx[8];
#pragma unroll
    for (int kt = 0; kt < 16; ++kt)
#pragma unroll
        for (int i = 0; i < 8; ++i)
            Bh[kt][i] = f2b(Wh[(size_t)(kt * 32 + quad * 8 + i) * 2048 + col]);
#pragma unroll
    for (int kt = 0; kt < 8; ++kt)
#pragma unroll
        for (int i = 0; i < 8; ++i)
            Bx[kt][i] = f2b(Wi[(size_t)(kt * 32 + quad * 8 + i) * 2048 + col]);
    const float bv = bvec[col];

    bf16x8 Ax[8];
    load_x_frags(emb, idx[arow * SEQ], quad, Ax);

    // staging mapping: wave 'gate' owns rows gate*4+quad; lane covers units l16+16i
    const int srow = gate * 4 + quad;

    // update threads (tid<128): register-resident c state (2 cells)
    const int rr = tid >> 3, u8 = tid & 7, c2 = u8 * 2;
    float cs0 = 0.f, cs1 = 0.f;

    for (int t = 0; t < SEQ; ++t) {
        const unsigned long long* rbase =
            hbuf + ((size_t)((t & 1) * 4 + grp) * 16 + srow) * 256 + l16;

        unsigned long long v[16];
        if (t > 0) {   // issue staging loads immediately (overlap x-MFMA + propagation)
#pragma unroll
            for (int i = 0; i < 16; ++i)
                v[i] = __hip_atomic_load(rbase + i * 16,
                                         __ATOMIC_RELAXED, __HIP_MEMORY_SCOPE_AGENT);
        }

        // ---- x contribution (Ax prefetched at end of previous step) ----
        f32x4 a0 = {0.f, 0.f, 0.f, 0.f}, a1 = {0.f, 0.f, 0.f, 0.f};
#pragma unroll
        for (int kt = 0; kt < 8; kt += 2) {
            a0 = __builtin_amdgcn_mfma_f32_16x16x32_bf16(Ax[kt],     Bx[kt],     a0, 0, 0, 0);
            a1 = __builtin_amdgcn_mfma_f32_16x16x32_bf16(Ax[kt + 1], Bx[kt + 1], a1, 0, 0, 0);
        }

        if (t > 0) {
            // ---- wave-uniform tag poll: batched reloads, no divergence ----
            const unsigned tg = (unsigned)t;
            while (true) {
                bool ok = true;
#pragma unroll
                for (int i = 0; i < 16; ++i)
                    ok = ok && ((unsigned)(v[i] >> 32) == tg);
                if (__ballot(ok) == ~0ull) break;
#pragma unroll
                for (int i = 0; i < 16; ++i)
                    v[i] = __hip_atomic_load(rbase + i * 16,
                                             __ATOMIC_RELAXED, __HIP_MEMORY_SCOPE_AGENT);
            }
#pragma unroll
            for (int i = 0; i < 16; ++i)
                *(unsigned*)&hstage[srow][(l16 + i * 16) * 2] = (unsigned)v[i];
        }
        __syncthreads();   // barrier1: hstage ready (nothing else in flight)

        if (t > 0) {
#pragma unroll
            for (int kt = 0; kt < 16; kt += 2) {
                bf16x8 ha = *(const bf16x8*)&hstage[l16][kt * 32 + quad * 8];
                bf16x8 hb = *(const bf16x8*)&hstage[l16][(kt + 1) * 32 + quad * 8];
                a0 = __builtin_amdgcn_mfma_f32_16x16x32_bf16(ha, Bh[kt],     a0, 0, 0, 0);
                a1 = __builtin_amdgcn_mfma_f32_16x16x32_bf16(hb, Bh[kt + 1], a1, 0, 0, 0);
            }
        }

        // ---- activation: C layout row=(quad*4+r), col=l16 ----
#pragma unroll
        for (int r = 0; r < 4; ++r) {
            float z = a0[r] + a1[r] + bv;
            gbuf[gate][quad * 4 + r][l16] = (gate == 2) ? fast_tanh(z) : fast_sig(z);
        }
        __syncthreads();   // barrier2: gates ready (nothing in flight)

        // ---- c/h update (waves 0,1); tagged 8B stores, fire-and-forget ----
        if (tid < 128) {
            float h0, h1;
            {
                float i0 = gbuf[0][rr][c2], f0 = gbuf[1][rr][c2];
                float gg = gbuf[2][rr][c2], o0 = gbuf[3][rr][c2];
                float cc = f0 * cs0 + i0 * gg;
                cs0 = cc;
                h0 = o0 * fast_tanh(cc);
            }
            {
                float i1 = gbuf[0][rr][c2 + 1], f1 = gbuf[1][rr][c2 + 1];
                float gg = gbuf[2][rr][c2 + 1], o1 = gbuf[3][rr][c2 + 1];
                float cc = f1 * cs1 + i1 * gg;
                cs1 = cc;
                h1 = o1 * fast_tanh(cc);
            }
            unsigned pv = (unsigned)(unsigned short)f2b(h0) |
                          ((unsigned)(unsigned short)f2b(h1) << 16);
            unsigned long long val = (unsigned long long)pv |
                                     ((unsigned long long)(unsigned)(t + 1) << 32);
            unsigned long long* dst = hbuf +
                ((size_t)(((t + 1) & 1) * 4 + grp) * 16 + rr) * 256 + j * 8 + u8;
            __hip_atomic_store(dst, val, __ATOMIC_RELAXED, __HIP_MEMORY_SCOPE_AGENT);
            if (t == SEQ - 1)
                *(unsigned*)&hfinal[(size_t)(grp * 16 + rr) * HID + j * 16 + c2] = pv;
        }

        // ---- emb prefetch for t+1: issued after stores; drains inside next
        //      step's poll wait, never at a barrier ----
        if (t + 1 < SEQ) {
            int nx = idx[arow * SEQ + t + 1];
            load_x_frags(emb, nx, quad, Ax);
        }
    }
}

// ---------------------------------------------------------------------------
// y = tanh(A[64x512](bf16) @ W[512x512](f32) + bias) -> out bf16 [64][512]
// ---------------------------------------------------------------------------
__global__ __launch_bounds__(256, 1) void gemm_tanh_kernel(
    const unsigned short* __restrict__ A, const float* __restrict__ W,
    const float* __restrict__ bias, unsigned short* __restrict__ out)
{
    const int tid = threadIdx.x, lane = tid & 63, wave = tid >> 6;
    const int quad = lane >> 4, l16 = lane & 15;
    const int col = blockIdx.x * 16 + l16;
    bf16x8 Bw[16];
#pragma unroll
    for (int kt = 0; kt < 16; ++kt)
#pragma unroll
        for (int i = 0; i < 8; ++i)
            Bw[kt][i] = f2b(W[(size_t)(kt * 32 + quad * 8 + i) * HID + col]);
    f32x4 acc = {0.f, 0.f, 0.f, 0.f};
#pragma unroll
    for (int kt = 0; kt < 16; ++kt) {
        bf16x8 a = *(const bf16x8*)(A + (size_t)(wave * 16 + l16) * HID + kt * 32 + quad * 8);
        acc = __builtin_amdgcn_mfma_f32_16x16x32_bf16(a, Bw[kt], acc, 0, 0, 0);
    }
    const float bvv = bias[col];
#pragma unroll
    for (int r = 0; r < 4; ++r) {
        float y = fast_tanh(acc[r] + bvv);
        out[(size_t)(wave * 16 + quad * 4 + r) * HID + col] = (unsigned short)f2b(y);
    }
}

// ---------------------------------------------------------------------------
// logits = A[64x512](bf16) @ W3[512x50257](f32) + b3 -> f32 [64][50257]
// LDS-staged W3 tiles: coalesced float4 HBM reads.
// ---------------------------------------------------------------------------
__global__ __launch_bounds__(256, 2) void logits_kernel(
    const unsigned short* __restrict__ A, const float* __restrict__ W3,
    const float* __restrict__ b3, float* __restrict__ outL)
{
    const int tid = threadIdx.x, lane = tid & 63, wave = tid >> 6;
    const int quad = lane >> 4, l16 = lane & 15;
    const int c0 = blockIdx.x * 64;
    const int col = c0 + wave * 16 + l16;
    const bool cok = col < VOCAB;
    const int colc = cok ? col : (VOCAB - 1);

    __shared__ unsigned short wt[256][68];

    f32x4 acc[4];
#pragma unroll
    for (int rt = 0; rt < 4; ++rt) acc[rt] = (f32x4){0.f, 0.f, 0.f, 0.f};

    const int kr = tid >> 4;
    const int cg = (tid & 15) * 4;

    for (int kc = 0; kc < 2; ++kc) {
#pragma unroll 4
        for (int it = 0; it < 16; ++it) {
            const int k = it * 16 + kr;
            const int gc = c0 + cg;
            float4 wv;
            if (gc + 3 < VOCAB) {
                wv = *(const float4*)&W3[(size_t)(kc * 256 + k) * VOCAB + gc];
            } else {
                const float* Wr = &W3[(size_t)(kc * 256 + k) * VOCAB];
                wv.x = (gc + 0 < VOCAB) ? Wr[gc + 0] : 0.f;
                wv.y = (gc + 1 < VOCAB) ? Wr[gc + 1] : 0.f;
                wv.z = (gc + 2 < VOCAB) ? Wr[gc + 2] : 0.f;
                wv.w = (gc + 3 < VOCAB) ? Wr[gc + 3] : 0.f;
            }
            unsigned short* d = &wt[k][cg];
            d[0] = (unsigned short)f2b(wv.x);
            d[1] = (unsigned short)f2b(wv.y);
            d[2] = (unsigned short)f2b(wv.z);
            d[3] = (unsigned short)f2b(wv.w);
        }
        __syncthreads();
        bf16x8 Bw[8];
#pragma unroll
        for (int kt = 0; kt < 8; ++kt)
#pragma unroll
            for (int i = 0; i < 8; ++i)
                Bw[kt][i] = (short)wt[kt * 32 + quad * 8 + i][wave * 16 + l16];
#pragma unroll
        for (int rt = 0; rt < 4; ++rt)
#pragma unroll
            for (int kt = 0; kt < 8; ++kt) {
                bf16x8 a = *(const bf16x8*)(A + (size_t)(rt * 16 + l16) * HID +
                                            kc * 256 + kt * 32 + quad * 8);
                acc[rt] = __builtin_amdgcn_mfma_f32_16x16x32_bf16(a, Bw[kt], acc[rt], 0, 0, 0);
            }
        __syncthreads();
    }
    const float bvv = b3[colc];
    if (cok) {
#pragma unroll
        for (int rt = 0; rt < 4; ++rt)
#pragma unroll
            for (int r = 0; r < 4; ++r)
                outL[(size_t)(rt * 16 + quad * 4 + r) * VOCAB + col] = acc[rt][r] + bvv;
    }
}

// ---------------------------------------------------------------------------
// row-wise log_softmax over [64][50257], float4 main loop
// ---------------------------------------------------------------------------
__global__ __launch_bounds__(256, 1) void lsm_kernel(
    const float* __restrict__ lg, float* __restrict__ out)
{
    const int row = blockIdx.x;
    const float* L = lg + (size_t)row * VOCAB;
    const float4* L4 = (const float4*)L;
    const int nv4 = VOCAB / 4;

    float m = -1e30f;
    for (int i = threadIdx.x; i < nv4; i += 256) {
        float4 v = L4[i];
        m = fmaxf(fmaxf(fmaxf(m, v.x), fmaxf(v.y, v.z)), v.w);
    }
    if (threadIdx.x == 0) m = fmaxf(m, L[VOCAB - 1]);
#pragma unroll
    for (int o = 32; o; o >>= 1) m = fmaxf(m, __shfl_xor(m, o));
    __shared__ float red[4], red2[4];
    if ((threadIdx.x & 63) == 0) red[threadIdx.x >> 6] = m;
    __syncthreads();
    m = fmaxf(fmaxf(red[0], red[1]), fmaxf(red[2], red[3]));

    float s = 0.f;
    for (int i = threadIdx.x; i < nv4; i += 256) {
        float4 v = L4[i];
        s += __expf(v.x - m) + __expf(v.y - m) + __expf(v.z - m) + __expf(v.w - m);
    }
    if (threadIdx.x == 0) s += __expf(L[VOCAB - 1] - m);
#pragma unroll
    for (int o = 32; o; o >>= 1) s += __shfl_xor(s, o);
    if ((threadIdx.x & 63) == 0) red2[threadIdx.x >> 6] = s;
    __syncthreads();
    s = red2[0] + red2[1] + red2[2] + red2[3];
    const float ls = m + __logf(s);

    float* O = out + (size_t)row * VOCAB;
    float4* O4 = (float4*)O;
    for (int i = threadIdx.x; i < nv4; i += 256) {
        float4 v = L4[i];
        O4[i] = (float4){v.x - ls, v.y - ls, v.z - ls, v.w - ls};
    }
    if (threadIdx.x == 0) O[VOCAB - 1] = L[VOCAB - 1] - ls;
}

extern "C" void kernel_launch(void* const* d_in, const int* in_sizes, int n_in,
                              void* d_out, int out_size, void* d_ws, size_t ws_size,
                              hipStream_t stream) {
    (void)in_sizes; (void)n_in; (void)out_size; (void)ws_size;
    const int*   idx = (const int*)d_in[0];
    const float* emb = (const float*)d_in[1];
    const float* Wi  = (const float*)d_in[2];
    const float* Wh  = (const float*)d_in[3];
    const float* b   = (const float*)d_in[4];
    const float* W1  = (const float*)d_in[5];
    const float* b1  = (const float*)d_in[6];
    const float* W2  = (const float*)d_in[7];
    const float* b2  = (const float*)d_in[8];
    const float* W3  = (const float*)d_in[9];
    const float* b3  = (const float*)d_in[10];
    float* out = (float*)d_out;

    // ws layout (time-disjoint aliasing, 13.13 MB total):
    //   [0, 256K)           hbuf   (lstm only) -- later reused by y1/y2
    //   [0, 64K)            y1     (gemm1 out / gemm2 in)
    //   [64K, 128K)         y2     (gemm2 out / logits in)
    //   [256K, 320K)        hfinal (lstm out / gemm1 in) -- dead before logits writes
    //   [256K, 256K+12.87M) logits (logits out / lsm in)
    char* w = (char*)d_ws;
    unsigned long long* hbuf   = (unsigned long long*)w;
    unsigned short*     y1     = (unsigned short*)w;
    unsigned short*     y2     = (unsigned short*)(w + 65536);
    unsigned short*     hfinal = (unsigned short*)(w + 262144);
    float*              logits = (float*)(w + 262144);

    lstm_kernel<<<128, 256, 0, stream>>>(idx, emb, Wi, Wh, b, hbuf, hfinal);
    gemm_tanh_kernel<<<HID / 16, 256, 0, stream>>>(hfinal, W1, b1, y1);
    gemm_tanh_kernel<<<HID / 16, 256, 0, stream>>>(y1, W2, b2, y2);
    logits_kernel<<<(VOCAB + 63) / 64, 256, 0, stream>>>(y2, W3, b3, logits);
    lsm_kernel<<<BATCH, 256, 0, stream>>>(logits, out);
}